// Round 12
// baseline (157.394 us; speedup 1.0000x reference)
//
#include <hip/hip_runtime.h>

#define BB 4
#define PP 8
#define NN 4096
#define EE 65536
#define SLOTS 48   // Poisson(16) degree; P(deg>=48) ~ 1e-11 -> safe, clamped anyway

// ---------------- workspace layout (bytes) ----------------
// h      : [B*P][N][64] f32 @ 0          (33,554,432)
// deg    : [B][N] int       @ 33554432   (65,536)  cursor == final degree
// bucket : [B][N][48] int   @ 33619968   (3,145,728)
// total ~ 36.8 MB
#define OFF_DEG    33554432u
#define OFF_BUCKET 33619968u

// ---------------- fused: GEMM (blocks 0..2047) + bucket fill (2048..3071) ----
// GEMM: h[row][c] = sum_k x[row][k] * W[k][c]; 64 rows staged in LDS with one
// sync, W column in 64 VGPRs/lane, broadcast ds_read_b128, 4 FMA chains.
// Block->frame remap: block bid (XCD bid&7) computes frame 4*(bid&7)+(bid>>3)/64,
// so each frame is written through the L2 of the XCD that k_agg reads it on.
// Bucket: pos = atomicAdd(deg[b][dst]); bucket[b][dst][pos] = src (cursor==deg).
__global__ __launch_bounds__(256) void k_fused(const float* __restrict__ x,
                                               const float* __restrict__ W,
                                               float* __restrict__ h,
                                               const int* __restrict__ ei,
                                               int* __restrict__ deg,
                                               int* __restrict__ bucket) {
    if (blockIdx.x < 2048) {
        // ---- GEMM part ----
        __shared__ __align__(16) float xl[64 * 64];
        const int lane = threadIdx.x & 63;
        const int wv   = threadIdx.x >> 6;

        float wreg[64];
#pragma unroll
        for (int k = 0; k < 64; ++k) wreg[k] = W[k * 64 + lane];

        const int bid = blockIdx.x;
        const int xcd = bid & 7;
        const int kk  = bid >> 3;               // 0..255
        const int f   = xcd * 4 + (kk >> 6);    // frame 0..31 (owned by this XCD)
        const int rb  = kk & 63;                // 64-row block within frame
        const size_t base = ((size_t)f * NN + rb * 64) * 64;

        const float4* xg = (const float4*)(x + base);
        float4* xs = (float4*)xl;
#pragma unroll
        for (int j = 0; j < 4; ++j)
            xs[j * 256 + threadIdx.x] = xg[j * 256 + threadIdx.x];
        __syncthreads();

        float* hb = h + base;
#pragma unroll 1
        for (int r0 = wv * 16; r0 < wv * 16 + 16; r0 += 2) {
            const float4* xa = (const float4*)&xl[r0 * 64];
            const float4* xb = (const float4*)&xl[(r0 + 1) * 64];
            float a0 = 0.f, a1 = 0.f, b0 = 0.f, b1 = 0.f;
#pragma unroll
            for (int k4 = 0; k4 < 16; k4 += 2) {
                const float4 va0 = xa[k4], va1 = xa[k4 + 1];
                const float4 vb0 = xb[k4], vb1 = xb[k4 + 1];
                a0 = fmaf(va0.x, wreg[4 * k4 + 0], a0);
                a0 = fmaf(va0.y, wreg[4 * k4 + 1], a0);
                a0 = fmaf(va0.z, wreg[4 * k4 + 2], a0);
                a0 = fmaf(va0.w, wreg[4 * k4 + 3], a0);
                a1 = fmaf(va1.x, wreg[4 * k4 + 4], a1);
                a1 = fmaf(va1.y, wreg[4 * k4 + 5], a1);
                a1 = fmaf(va1.z, wreg[4 * k4 + 6], a1);
                a1 = fmaf(va1.w, wreg[4 * k4 + 7], a1);
                b0 = fmaf(vb0.x, wreg[4 * k4 + 0], b0);
                b0 = fmaf(vb0.y, wreg[4 * k4 + 1], b0);
                b0 = fmaf(vb0.z, wreg[4 * k4 + 2], b0);
                b0 = fmaf(vb0.w, wreg[4 * k4 + 3], b0);
                b1 = fmaf(vb1.x, wreg[4 * k4 + 4], b1);
                b1 = fmaf(vb1.y, wreg[4 * k4 + 5], b1);
                b1 = fmaf(vb1.z, wreg[4 * k4 + 6], b1);
                b1 = fmaf(vb1.w, wreg[4 * k4 + 7], b1);
            }
            hb[r0 * 64 + lane] = a0 + a1;
            hb[(r0 + 1) * 64 + lane] = b0 + b1;
        }
    } else {
        // ---- bucket-fill part ----
        const int idx = (blockIdx.x - 2048) * 256 + threadIdx.x;  // 0 .. B*E
        const int b = idx >> 16;
        const int e = idx & (EE - 1);
        const int s = ei[(size_t)b * 2 * EE + e];
        const int d = ei[(size_t)b * 2 * EE + EE + e];
        const int pos = atomicAdd(&deg[b * NN + d], 1);
        if (pos < SLOTS)
            bucket[(size_t)(b * NN + d) * SLOTS + pos] = s;
    }
}

// ---------------- aggregation + bias + PReLU ---------------------------------
// One wave per (frame-pair, node), pair-ordered grid: XCD x sweeps its frames
// 4x..4x+3 in two temporal phases of 2 MB hot-set (round-6 locality), while
// each iteration gathers 4 edges x 2 frames = 8 independent h loads (round-8
// MLP). Edge weight rsqrtf(deg[src]+1) on the fly; deg table L1/L2-resident.
// GRID: 16 pairs x 4096 nodes = 65536 waves = 16384 blocks (4 waves/block).
__global__ __launch_bounds__(256) void k_agg(const float* __restrict__ h,
                                             const int* __restrict__ deg,
                                             const int* __restrict__ bucket,
                                             const float* __restrict__ bias,
                                             const float* __restrict__ pa,
                                             float* __restrict__ out) {
    const int lane = threadIdx.x & 63;
    const int wv   = threadIdx.x >> 6;
    const int g    = blockIdx.x;             // 16384 blocks
    const int xcd  = g & 7;
    const int idx  = g >> 3;                 // 0..2047
    const int pair = xcd * 2 + (idx >> 10);  // 0..15
    const int bp0  = pair * 2;               // frames bp0, bp0+1
    const int b    = bp0 >> 3;
    const int i    = ((idx & 1023) << 2) + wv;

    const int* dgb = deg + b * NN;
    const int  ndr = dgb[i];
    const int  nd  = min(ndr, SLOTS);
    const float di = rsqrtf((float)(ndr + 1));
    const int* bk  = bucket + (size_t)(b * NN + i) * SLOTS;
    const float* h0 = h + ((size_t)bp0 << 18);
    const float* h1 = h0 + (1u << 18);

    const int self = (i << 6) + lane;  // 32-bit voffset (< 1 MB per frame)
    float a00 = di * h0[self], a01 = 0.f, a02 = 0.f, a03 = 0.f;
    float a10 = di * h1[self], a11 = 0.f, a12 = 0.f, a13 = 0.f;

    int e = 0;
    for (; e + 4 <= nd; e += 4) {
        const int4 jj = *(const int4*)(bk + e);  // 16 B-aligned (row base 192 B)
        const float w0 = rsqrtf((float)(dgb[jj.x] + 1));
        const float w1 = rsqrtf((float)(dgb[jj.y] + 1));
        const float w2 = rsqrtf((float)(dgb[jj.z] + 1));
        const float w3 = rsqrtf((float)(dgb[jj.w] + 1));
        const int o0 = (jj.x << 6) + lane;
        const int o1 = (jj.y << 6) + lane;
        const int o2 = (jj.z << 6) + lane;
        const int o3 = (jj.w << 6) + lane;
        a00 = fmaf(w0, h0[o0], a00);
        a10 = fmaf(w0, h1[o0], a10);
        a01 = fmaf(w1, h0[o1], a01);
        a11 = fmaf(w1, h1[o1], a11);
        a02 = fmaf(w2, h0[o2], a02);
        a12 = fmaf(w2, h1[o2], a12);
        a03 = fmaf(w3, h0[o3], a03);
        a13 = fmaf(w3, h1[o3], a13);
    }
    for (; e < nd; ++e) {
        const int j = bk[e];
        const int o = (j << 6) + lane;
        const float w = rsqrtf((float)(dgb[j] + 1));
        a00 = fmaf(w, h0[o], a00);
        a10 = fmaf(w, h1[o], a10);
    }
    const float acc0 = (a00 + a01) + (a02 + a03);
    const float acc1 = (a10 + a11) + (a12 + a13);

    const float bs = bias[lane];
    const float al = pa[0];
    float r0 = fmaf(di, acc0, bs);
    float r1 = fmaf(di, acc1, bs);
    r0 = r0 >= 0.f ? r0 : al * r0;
    r1 = r1 >= 0.f ? r1 : al * r1;
    out[((size_t)bp0 << 18) + self] = r0;
    out[(((size_t)bp0 + 1) << 18) + self] = r1;
}

extern "C" void kernel_launch(void* const* d_in, const int* in_sizes, int n_in,
                              void* d_out, int out_size, void* d_ws, size_t ws_size,
                              hipStream_t stream) {
    const float* x    = (const float*)d_in[0];
    const int*   ei   = (const int*)d_in[1];
    const float* W    = (const float*)d_in[2];
    const float* bias = (const float*)d_in[3];
    const float* pa   = (const float*)d_in[4];
    float* out = (float*)d_out;

    char* ws = (char*)d_ws;
    float* h      = (float*)ws;
    int*   deg    = (int*)(ws + OFF_DEG);
    int*   bucket = (int*)(ws + OFF_BUCKET);

    // zero the degree/cursor table (64 KB); ws is re-poisoned before every call
    hipMemsetAsync(deg, 0, BB * NN * sizeof(int), stream);

    k_fused<<<3072, 256, 0, stream>>>(x, W, h, ei, deg, bucket);
    // 16 frame-pairs x 4096 nodes, 4 waves/block -> 16384 blocks (NOT /4!)
    k_agg<<<(BB * PP * NN) / 8, 256, 0, stream>>>(h, deg, bucket, bias, pa, out);
}